// Round 4
// baseline (378.234 us; speedup 1.0000x reference)
//
#include <hip/hip_runtime.h>
#include <hip/hip_bf16.h>
#include <stdint.h>

// Dims fixed by reference: L=2048, B=8, D=2048
#define L_SEQ 2048
#define BATCH 8
#define DIM   2048
#define M_DIM (L_SEQ * BATCH)   // 16384
#define N_DIM DIM
#define K_DIM DIM

typedef short bf16x8  __attribute__((ext_vector_type(8)));
typedef float f32x4   __attribute__((ext_vector_type(4)));
typedef float f32x16  __attribute__((ext_vector_type(16)));
typedef unsigned short u16x4 __attribute__((ext_vector_type(4)));

__device__ inline unsigned short f2bf_rn(float f) {
    unsigned int u = __float_as_uint(f);
    u += 0x7FFF + ((u >> 16) & 1);
    return (unsigned short)(u >> 16);
}

__device__ inline void gload16(const void* g, void* l) {
    __builtin_amdgcn_global_load_lds(
        (const __attribute__((address_space(1))) void*)g,
        (__attribute__((address_space(3))) void*)l, 16, 0, 0);
}

// ---------------- Kernel 1: W f32 -> bf16 ([e][d] == B^T [N][K]) -----------
__global__ void cvt_w_kernel(const float* __restrict__ W,
                             unsigned short* __restrict__ Wb) {
    int i = blockIdx.x * 256 + threadIdx.x;
    const float4 v = *reinterpret_cast<const float4*>(W + (size_t)i * 4);
    u16x4 r;
    r.x = f2bf_rn(v.x); r.y = f2bf_rn(v.y);
    r.z = f2bf_rn(v.z); r.w = f2bf_rn(v.w);
    *reinterpret_cast<u16x4*>(Wb + (size_t)i * 4) = r;
}

// ---------------- Kernel 2: chunked EMA scan (float2, chunk=128, LB=64) ----
// f = sigmoid(p) <= 0.7311 -> f^64 < 2e-9: lookback truncation negligible.
// Measured ~47 us (BW floor ~43) — keep.
#define SCH 128
#define SLB 64
__global__ void ema_scan_kernel(const float* __restrict__ x,
                                const float* __restrict__ xml,
                                const float* __restrict__ fparam,
                                unsigned short* __restrict__ xm) {
    int g  = blockIdx.x * 256 + threadIdx.x;   // 131072 threads
    int dp = (g & 1023) * 2;
    int b  = (g >> 10) & (BATCH - 1);
    int ch = g >> 13;

    float2 pv = *reinterpret_cast<const float2*>(fparam + dp);
    const float f0 = 1.0f / (1.0f + expf(-pv.x));
    const float f1 = 1.0f / (1.0f + expf(-pv.y));
    float2 xlv = *reinterpret_cast<const float2*>(xml + b * DIM + dp);
    const float om0 = 1.0f - f0, om1 = 1.0f - f1;

    const int t0 = ch * SCH;
    int ts = t0 - SLB; if (ts < 0) ts = 0;
    const int stride2 = (BATCH * DIM) / 2;

    const float2* xp = reinterpret_cast<const float2*>(x) +
                       (size_t)ts * stride2 + (b * DIM + dp) / 2;
    float c0 = 0.0f, c1 = 0.0f;
    #pragma unroll 8
    for (int t = ts; t < t0; ++t) {
        float2 v = *xp;
        c0 = fmaf(c0, f0, v.x);
        c1 = fmaf(c1, f1, v.y);
        xp += stride2;
    }
    float pw0 = powf(f0, (float)(t0 + 1));
    float pw1 = powf(f1, (float)(t0 + 1));
    ushort2* op = reinterpret_cast<ushort2*>(xm + (size_t)t0 * BATCH * DIM + b * DIM + dp);
    #pragma unroll 8
    for (int k = 0; k < SCH; ++k) {
        float2 v = *xp;
        c0 = fmaf(c0, f0, v.x);
        c1 = fmaf(c1, f1, v.y);
        ushort2 r;
        r.x = f2bf_rn(fmaf(xlv.x, pw0, om0 * c0));
        r.y = f2bf_rn(fmaf(xlv.y, pw1, om1 * c1));
        *op = r;
        pw0 *= f0; pw1 *= f1;
        xp += stride2; op += stride2;
    }
}

// ---------------- Kernel 3: 256x256 8-phase GEMM, 32x32x16 MFMA ------------
// C[M,N] = A[M,K] * Bt[N,K]^T.  512 thr (8 waves 2Mx4N), BK=64, 128KB LDS
// double-buffer, XOR swizzle (16B slot ^= row&7) on pre-swizzled global
// source + swizzled ds_read (LDS dest linear).
// Per wave: rows {qa*128 + wr*64 + rb*32}, cols {qb*128 + wn*32}.
// acc[4][2] f32x16 (rblk = qa*2+rb, cblk = qb).  8 x 32x32x16 MFMA / phase.
// Quadrant walk (0,0)->(0,1)->(1,1)->(1,0); A reloaded on qa flip; BOTH
// B-halves held in regs (bfr0/bfr1) -> 24 ds_read_b128 per group.
// Stage order A0',B0',B1',A1'; vmcnt(4) at each phase end = minimal 3-phase
// slack for soonest-consumed half. Peel drains 2,0,0,0.
#define NT_K (K_DIM / 64)   // 32 K-tiles
#define NI   (NT_K / 2)     // 16 iterations

__global__ void __launch_bounds__(512, 2)
gemm8_kernel(const unsigned short* __restrict__ A,
             const unsigned short* __restrict__ Bt,
             float* __restrict__ C) {
    extern __shared__ __attribute__((aligned(16))) char smem[];   // 131072 B

    // bijective XCD swizzle (nwg=512, 512%8==0)
    int bid = blockIdx.x;
    int swz = (bid & 7) * 64 + (bid >> 3);
    const int tm = swz >> 3;      // 64 M-tiles
    const int tn = swz & 7;       // 8  N-tiles

    const int tid  = threadIdx.x;
    const int lane = tid & 63;
    const int w    = tid >> 6;
    const int wr   = w >> 2;      // 0..1
    const int wn   = w & 3;       // 0..3

    const int aoff0 = (tid >> 3) * (K_DIM * 2) + (((tid & 7) ^ ((tid >> 3) & 7)) * 16);
    const int aoff1 = aoff0 + 64 * (K_DIM * 2);
    const char* gAc = (const char*)(A  + (size_t)tm * 256 * K_DIM);
    const char* gBc = (const char*)(Bt + (size_t)tn * 256 * K_DIM);

#define STAGE_A(bs, ha, t) do {                                              \
        const char* _s = gAc + (size_t)((ha) * 128) * (K_DIM * 2) + (size_t)(t) * 128; \
        char* _d = smem + (bs) * 65536 + (ha) * 16384 + tid * 16;            \
        gload16(_s + aoff0, _d);                                             \
        gload16(_s + aoff1, _d + 8192);                                      \
    } while (0)
#define STAGE_B(bs, hb, t) do {                                              \
        const char* _s = gBc + (size_t)((hb) * 128) * (K_DIM * 2) + (size_t)(t) * 128; \
        char* _d = smem + (bs) * 65536 + 32768 + (hb) * 16384 + tid * 16;    \
        gload16(_s + aoff0, _d);                                             \
        gload16(_s + aoff1, _d + 8192);                                      \
    } while (0)

    // fragment addressing (32x32x16): A row = lane&31 within 32-block,
    // k-elem = (lane>>5)*8 + j  -> byte col = ks*32 + (lane>>5)*16
    const int ra    = wr * 64 + (lane & 31);   // + qa*128 + rb*32
    const int rbB   = wn * 32 + (lane & 31);   // + qb*128
    const int kbyte = (lane >> 5) * 16;
    const int cxor  = (lane & 7) << 4;         // (row&7)<<4 (blocks are %8==0)

    f32x16 acc[4][2];
    #pragma unroll
    for (int r = 0; r < 4; ++r)
        #pragma unroll
        for (int c = 0; c < 2; ++c)
            #pragma unroll
            for (int e = 0; e < 16; ++e)
                acc[r][c][e] = 0.f;

    bf16x8 afr[2][4];    // A frags: [rb][ks], current qa
    bf16x8 bfr0[4];      // B frags qb=0: [ks]
    bf16x8 bfr1[4];      // B frags qb=1: [ks]

#define LOAD_A(qa, bs) do {                                                  \
        const char* _ab = smem + (bs) * 65536;                               \
        _Pragma("unroll") for (int rb = 0; rb < 2; ++rb) {                   \
            int _r = (qa) * 128 + ra + rb * 32;                              \
            _Pragma("unroll") for (int ks = 0; ks < 4; ++ks)                 \
                afr[rb][ks] = *(const bf16x8*)(_ab + _r * 128 +              \
                                               ((ks * 32 + kbyte) ^ cxor));  \
        }                                                                    \
    } while (0)
#define LOAD_B(qb, dst, bs) do {                                             \
        const char* _bb = smem + (bs) * 65536 + 32768;                       \
        int _rn = (qb) * 128 + rbB;                                          \
        _Pragma("unroll") for (int ks = 0; ks < 4; ++ks)                     \
            dst[ks] = *(const bf16x8*)(_bb + _rn * 128 +                     \
                                       ((ks * 32 + kbyte) ^ cxor));          \
    } while (0)

#define PHASE_MFMA(qa, bsel, VN, ...) do {                                   \
        __VA_ARGS__;                                                         \
        __builtin_amdgcn_s_barrier();                                        \
        __builtin_amdgcn_s_setprio(1);                                       \
        _Pragma("unroll") for (int rb = 0; rb < 2; ++rb)                     \
            _Pragma("unroll") for (int ks = 0; ks < 4; ++ks)                 \
                acc[(qa) * 2 + rb][bsel] =                                   \
                    __builtin_amdgcn_mfma_f32_32x32x16_bf16(                 \
                        afr[rb][ks], (bsel) ? bfr1[ks] : bfr0[ks],           \
                        acc[(qa) * 2 + rb][bsel], 0, 0, 0);                  \
        __builtin_amdgcn_s_setprio(0);                                       \
        asm volatile("s_waitcnt vmcnt(" #VN ")" ::: "memory");               \
        __builtin_amdgcn_s_barrier();                                        \
    } while (0)

    // group per buf: (0,0)->(0,1)->(1,1)->(1,0); phase 4 needs no ds_reads
#define GROUP(bs, S1, S2, S3, S4, V1, V2, V3, V4) do {                       \
        LOAD_A(0, bs); LOAD_B(0, bfr0, bs);                                  \
        PHASE_MFMA(0, 0, V1, S1);                                            \
        LOAD_B(1, bfr1, bs);                                                 \
        PHASE_MFMA(0, 1, V2, S2);                                            \
        LOAD_A(1, bs);                                                       \
        PHASE_MFMA(1, 1, V3, S3);                                            \
        PHASE_MFMA(1, 0, V4, S4);                                            \
    } while (0)

    // prologue: tile 0 -> buf0
    STAGE_A(0, 0, 0); STAGE_B(0, 0, 0); STAGE_B(0, 1, 0); STAGE_A(0, 1, 0);
    asm volatile("s_waitcnt vmcnt(4)" ::: "memory");
    __builtin_amdgcn_s_barrier();

    for (int i = 0; i < NI - 1; ++i) {
        const int t1 = 2 * i + 1, t2 = 2 * i + 2;
        GROUP(0, STAGE_A(1, 0, t1), STAGE_B(1, 0, t1),
                 STAGE_B(1, 1, t1), STAGE_A(1, 1, t1), 4, 4, 4, 4);
        GROUP(1, STAGE_A(0, 0, t2), STAGE_B(0, 0, t2),
                 STAGE_B(0, 1, t2), STAGE_A(0, 1, t2), 4, 4, 4, 4);
    }
    GROUP(0, STAGE_A(1, 0, NT_K - 1), STAGE_B(1, 0, NT_K - 1),
             STAGE_B(1, 1, NT_K - 1), STAGE_A(1, 1, NT_K - 1), 4, 4, 4, 4);
    GROUP(1, (void)0, (void)0, (void)0, (void)0, 2, 0, 0, 0);

    // epilogue: 32x32 C/D layout col=lane&31, row=(reg&3)+8*(reg>>2)+4*(lane>>5)
    float* Cb = C + (size_t)(tm * 256) * N_DIM + tn * 256;
    const int col = lane & 31;
    const int r4  = (lane >> 5) * 4;
    #pragma unroll
    for (int rblk = 0; rblk < 4; ++rblk) {
        int rowbase = (rblk >> 1) * 128 + wr * 64 + (rblk & 1) * 32 + r4;
        #pragma unroll
        for (int qb = 0; qb < 2; ++qb) {
            int colbase = qb * 128 + wn * 32 + col;
            #pragma unroll
            for (int reg = 0; reg < 16; ++reg) {
                int row = rowbase + (reg & 3) + 8 * (reg >> 2);
                Cb[(size_t)row * N_DIM + colbase] = acc[rblk][qb][reg];
            }
        }
    }
#undef GROUP
#undef PHASE_MFMA
#undef LOAD_A
#undef LOAD_B
#undef STAGE_A
#undef STAGE_B
}

// ---------------- Launch ----------------------------------------------------
extern "C" void kernel_launch(void* const* d_in, const int* in_sizes, int n_in,
                              void* d_out, int out_size, void* d_ws, size_t ws_size,
                              hipStream_t stream) {
    const float* x   = (const float*)d_in[0];   // [L,B,D]
    const float* xml = (const float*)d_in[1];   // [B,D]
    const float* fp  = (const float*)d_in[2];   // [D]
    const float* W   = (const float*)d_in[3];   // [D,D] = [e][d]
    float* out = (float*)d_out;                 // [L,B,D] f32

    unsigned short* xmix = (unsigned short*)d_ws;                    // 67.1 MB
    unsigned short* wb   = xmix + (size_t)M_DIM * K_DIM;             // 8.4 MB

    (void)hipFuncSetAttribute(reinterpret_cast<const void*>(&gemm8_kernel),
                              hipFuncAttributeMaxDynamicSharedMemorySize, 131072);

    cvt_w_kernel<<<4096, 256, 0, stream>>>(W, wb);
    ema_scan_kernel<<<512, 256, 0, stream>>>(x, xml, fp, xmix);
    gemm8_kernel<<<(M_DIM / 256) * (N_DIM / 256), 512, 131072, stream>>>(xmix, wb, out);
}

// Round 5
// 360.522 us; speedup vs baseline: 1.0491x; 1.0491x over previous
//
#include <hip/hip_runtime.h>
#include <hip/hip_bf16.h>
#include <stdint.h>

// Dims fixed by reference: L=2048, B=8, D=2048
#define L_SEQ 2048
#define BATCH 8
#define DIM   2048
#define M_DIM (L_SEQ * BATCH)   // 16384
#define N_DIM DIM
#define K_DIM DIM

typedef short bf16x8 __attribute__((ext_vector_type(8)));
typedef float f32x4  __attribute__((ext_vector_type(4)));
typedef unsigned short u16x4 __attribute__((ext_vector_type(4)));

__device__ inline unsigned short f2bf_rn(float f) {
    unsigned int u = __float_as_uint(f);
    u += 0x7FFF + ((u >> 16) & 1);
    return (unsigned short)(u >> 16);
}

__device__ inline void gload16(const void* g, void* l) {
    __builtin_amdgcn_global_load_lds(
        (const __attribute__((address_space(1))) void*)g,
        (__attribute__((address_space(3))) void*)l, 16, 0, 0);
}

// ---------------- Kernel 1: W f32 -> bf16 ([e][d] == B^T [N][K]) -----------
__global__ void cvt_w_kernel(const float* __restrict__ W,
                             unsigned short* __restrict__ Wb) {
    int i = blockIdx.x * 256 + threadIdx.x;
    const float4 v = *reinterpret_cast<const float4*>(W + (size_t)i * 4);
    u16x4 r;
    r.x = f2bf_rn(v.x); r.y = f2bf_rn(v.y);
    r.z = f2bf_rn(v.z); r.w = f2bf_rn(v.w);
    *reinterpret_cast<u16x4*>(Wb + (size_t)i * 4) = r;
}

// ---------------- Kernel 2: chunked EMA scan (float2, chunk=128, LB=64) ----
// f = sigmoid(p) <= 0.7311 -> f^64 < 2e-9: lookback truncation negligible.
#define SCH 128
#define SLB 64
__global__ void ema_scan_kernel(const float* __restrict__ x,
                                const float* __restrict__ xml,
                                const float* __restrict__ fparam,
                                unsigned short* __restrict__ xm) {
    int g  = blockIdx.x * 256 + threadIdx.x;   // 131072 threads
    int dp = (g & 1023) * 2;
    int b  = (g >> 10) & (BATCH - 1);
    int ch = g >> 13;

    float2 pv = *reinterpret_cast<const float2*>(fparam + dp);
    const float f0 = 1.0f / (1.0f + expf(-pv.x));
    const float f1 = 1.0f / (1.0f + expf(-pv.y));
    float2 xlv = *reinterpret_cast<const float2*>(xml + b * DIM + dp);
    const float om0 = 1.0f - f0, om1 = 1.0f - f1;

    const int t0 = ch * SCH;
    int ts = t0 - SLB; if (ts < 0) ts = 0;
    const int stride2 = (BATCH * DIM) / 2;

    const float2* xp = reinterpret_cast<const float2*>(x) +
                       (size_t)ts * stride2 + (b * DIM + dp) / 2;
    float c0 = 0.0f, c1 = 0.0f;
    #pragma unroll 8
    for (int t = ts; t < t0; ++t) {
        float2 v = *xp;
        c0 = fmaf(c0, f0, v.x);
        c1 = fmaf(c1, f1, v.y);
        xp += stride2;
    }
    float pw0 = powf(f0, (float)(t0 + 1));
    float pw1 = powf(f1, (float)(t0 + 1));
    ushort2* op = reinterpret_cast<ushort2*>(xm + (size_t)t0 * BATCH * DIM + b * DIM + dp);
    #pragma unroll 8
    for (int k = 0; k < SCH; ++k) {
        float2 v = *xp;
        c0 = fmaf(c0, f0, v.x);
        c1 = fmaf(c1, f1, v.y);
        ushort2 r;
        r.x = f2bf_rn(fmaf(xlv.x, pw0, om0 * c0));
        r.y = f2bf_rn(fmaf(xlv.y, pw1, om1 * c1));
        *op = r;
        pw0 *= f0; pw1 *= f1;
        xp += stride2; op += stride2;
    }
}

// ---------------- Kernel 3: 256x256 GEMM, 16x16x32 MFMA, 4 fat phases ------
// C[M,N] = A[M,K] * Bt[N,K]^T.  512 thr (8 waves 2Mx4N), BK=64, 128KB LDS
// double-buffer, XOR swizzle (16B slot ^= row&7) on pre-swizzled global
// source + swizzled ds_read (LDS dest linear).  16x16 frag reads are 2
// lanes/bank (free); 32x32 frags would be 4-way conflicted (R4 regression).
// 2 phases per K-tile (4/iter), 32-MFMA clusters, 8 barriers/iter:
//   phase A: ds_read A0,B0,B1 (16 b128) | stage A0',B0',B1' (6 gload)
//            -> bar -> MFMA (0,0)+(0,1) x32 -> vmcnt(6) -> bar
//            [vmcnt(6) = current A1 landed, needed next phase]
//   phase B: ds_read A1 (8 b128)        | stage A1' (2 gload)
//            -> bar -> MFMA (1,0)+(1,1) x32 -> vmcnt(2) -> bar
//            [vmcnt(2) = A0',B0',B1' landed, needed next group]
// Every load has >= 1 full phase (~1200 cy) slack > ~900 cy HBM latency.
// Final group drains 0,0.
#define NT_K (K_DIM / 64)   // 32 K-tiles
#define NI   (NT_K / 2)     // 16 iterations

__global__ void __launch_bounds__(512, 2)
gemm8_kernel(const unsigned short* __restrict__ A,
             const unsigned short* __restrict__ Bt,
             float* __restrict__ C) {
    extern __shared__ __attribute__((aligned(16))) char smem[];   // 131072 B

    // bijective XCD swizzle (nwg=512, 512%8==0)
    int bid = blockIdx.x;
    int swz = (bid & 7) * 64 + (bid >> 3);
    const int tm = swz >> 3;      // 64 M-tiles
    const int tn = swz & 7;       // 8  N-tiles

    const int tid  = threadIdx.x;
    const int lane = tid & 63;
    const int w    = tid >> 6;
    const int wr   = w >> 2;      // 0..1
    const int wn   = w & 3;       // 0..3

    const int aoff0 = (tid >> 3) * (K_DIM * 2) + (((tid & 7) ^ ((tid >> 3) & 7)) * 16);
    const int aoff1 = aoff0 + 64 * (K_DIM * 2);
    const char* gAc = (const char*)(A  + (size_t)tm * 256 * K_DIM);
    const char* gBc = (const char*)(Bt + (size_t)tn * 256 * K_DIM);

#define STAGE_A(bs, ha, t) do {                                              \
        const char* _s = gAc + (size_t)((ha) * 128) * (K_DIM * 2) + (size_t)(t) * 128; \
        char* _d = smem + (bs) * 65536 + (ha) * 16384 + tid * 16;            \
        gload16(_s + aoff0, _d);                                             \
        gload16(_s + aoff1, _d + 8192);                                      \
    } while (0)
#define STAGE_B(bs, hb, t) do {                                              \
        const char* _s = gBc + (size_t)((hb) * 128) * (K_DIM * 2) + (size_t)(t) * 128; \
        char* _d = smem + (bs) * 65536 + 32768 + (hb) * 16384 + tid * 16;    \
        gload16(_s + aoff0, _d);                                             \
        gload16(_s + aoff1, _d + 8192);                                      \
    } while (0)

    const int ra   = wr * 64 + (lane & 15);
    const int rbB  = wn * 32 + (lane & 15);
    const int khi  = (lane >> 4) * 16;
    const int cxor = (lane & 7) << 4;

    f32x4 acc[8][4];
    #pragma unroll
    for (int m = 0; m < 8; ++m)
        #pragma unroll
        for (int n = 0; n < 4; ++n)
            acc[m][n] = (f32x4){0.f, 0.f, 0.f, 0.f};

    bf16x8 afr[4][2];    // current A-half frags
    bf16x8 bfr0[2][2];   // B frags qb=0
    bf16x8 bfr1[2][2];   // B frags qb=1

#define LOAD_A(qa, bs) do {                                                  \
        const char* _ab = smem + (bs) * 65536;                               \
        _Pragma("unroll") for (int m = 0; m < 4; ++m) {                      \
            int _r = (qa) * 128 + ra + m * 16;                               \
            _Pragma("unroll") for (int ks = 0; ks < 2; ++ks)                 \
                afr[m][ks] = *(const bf16x8*)(_ab + _r * 128 +               \
                                              ((ks * 64 + khi) ^ cxor));     \
        }                                                                    \
    } while (0)
#define LOAD_B(qb, dst, bs) do {                                             \
        const char* _bb = smem + (bs) * 65536 + 32768;                       \
        _Pragma("unroll") for (int n = 0; n < 2; ++n) {                      \
            int _rn = (qb) * 128 + rbB + n * 16;                             \
            _Pragma("unroll") for (int ks = 0; ks < 2; ++ks)                 \
                dst[n][ks] = *(const bf16x8*)(_bb + _rn * 128 +              \
                                              ((ks * 64 + khi) ^ cxor));     \
        }                                                                    \
    } while (0)

    // 32-MFMA cluster for quadrant row qa (both qb halves, B held in regs)
#define MFMA_ROW(qa)                                                         \
        _Pragma("unroll") for (int m = 0; m < 4; ++m)                        \
            _Pragma("unroll") for (int n = 0; n < 2; ++n)                    \
                _Pragma("unroll") for (int ks = 0; ks < 2; ++ks) {           \
                    acc[(qa) * 4 + m][n] =                                   \
                        __builtin_amdgcn_mfma_f32_16x16x32_bf16(             \
                            afr[m][ks], bfr0[n][ks],                         \
                            acc[(qa) * 4 + m][n], 0, 0, 0);                  \
                    acc[(qa) * 4 + m][2 + n] =                               \
                        __builtin_amdgcn_mfma_f32_16x16x32_bf16(             \
                            afr[m][ks], bfr1[n][ks],                         \
                            acc[(qa) * 4 + m][2 + n], 0, 0, 0);              \
                }

#define PHASE_END(VN)                                                        \
        asm volatile("s_waitcnt vmcnt(" #VN ")" ::: "memory");               \
        __builtin_amdgcn_s_barrier();

    // group = one K-tile (2 fat phases)
#define GROUP(bs, SA, SB, VA, VB) do {                                       \
        LOAD_A(0, bs); LOAD_B(0, bfr0, bs); LOAD_B(1, bfr1, bs);             \
        SA;                                                                  \
        __builtin_amdgcn_s_barrier();                                        \
        __builtin_amdgcn_s_setprio(1);                                       \
        MFMA_ROW(0)                                                          \
        __builtin_amdgcn_s_setprio(0);                                       \
        PHASE_END(VA)                                                        \
        LOAD_A(1, bs);                                                       \
        SB;                                                                  \
        __builtin_amdgcn_s_barrier();                                        \
        __builtin_amdgcn_s_setprio(1);                                       \
        MFMA_ROW(1)                                                          \
        __builtin_amdgcn_s_setprio(0);                                       \
        PHASE_END(VB)                                                        \
    } while (0)

    // prologue: tile 0 -> buf0 (order A0,B0,B1,A1); A0,B0,B1 landed at entry
    STAGE_A(0, 0, 0); STAGE_B(0, 0, 0); STAGE_B(0, 1, 0); STAGE_A(0, 1, 0);
    asm volatile("s_waitcnt vmcnt(2)" ::: "memory");
    __builtin_amdgcn_s_barrier();

    for (int i = 0; i < NI - 1; ++i) {
        const int t1 = 2 * i + 1, t2 = 2 * i + 2;
        GROUP(0, { STAGE_A(1, 0, t1); STAGE_B(1, 0, t1); STAGE_B(1, 1, t1); },
                 { STAGE_A(1, 1, t1); }, 6, 2);
        GROUP(1, { STAGE_A(0, 0, t2); STAGE_B(0, 0, t2); STAGE_B(0, 1, t2); },
                 { STAGE_A(0, 1, t2); }, 6, 2);
    }
    GROUP(0, { STAGE_A(1, 0, NT_K - 1); STAGE_B(1, 0, NT_K - 1);
               STAGE_B(1, 1, NT_K - 1); },
             { STAGE_A(1, 1, NT_K - 1); }, 6, 2);
    GROUP(1, (void)0, (void)0, 0, 0);

    // epilogue: C/D layout col=lane&15, row=(lane>>4)*4+j
    float* Cb = C + (size_t)(tm * 256) * N_DIM + tn * 256;
    const int col0 = lane & 15;
    const int rg   = (lane >> 4) * 4;
    #pragma unroll
    for (int qa2 = 0; qa2 < 2; ++qa2)
        #pragma unroll
        for (int m = 0; m < 4; ++m)
            #pragma unroll
            for (int j = 0; j < 4; ++j) {
                int row = qa2 * 128 + wr * 64 + m * 16 + rg + j;
                float* rp = Cb + (size_t)row * N_DIM;
                #pragma unroll
                for (int qb2 = 0; qb2 < 2; ++qb2)
                    #pragma unroll
                    for (int n = 0; n < 2; ++n)
                        rp[qb2 * 128 + wn * 32 + n * 16 + col0] =
                            acc[qa2 * 4 + m][qb2 * 2 + n][j];
            }
#undef GROUP
#undef PHASE_END
#undef MFMA_ROW
#undef LOAD_A
#undef LOAD_B
#undef STAGE_A
#undef STAGE_B
}

// ---------------- Launch ----------------------------------------------------
extern "C" void kernel_launch(void* const* d_in, const int* in_sizes, int n_in,
                              void* d_out, int out_size, void* d_ws, size_t ws_size,
                              hipStream_t stream) {
    const float* x   = (const float*)d_in[0];   // [L,B,D]
    const float* xml = (const float*)d_in[1];   // [B,D]
    const float* fp  = (const float*)d_in[2];   // [D]
    const float* W   = (const float*)d_in[3];   // [D,D] = [e][d]
    float* out = (float*)d_out;                 // [L,B,D] f32

    unsigned short* xmix = (unsigned short*)d_ws;                    // 67.1 MB
    unsigned short* wb   = xmix + (size_t)M_DIM * K_DIM;             // 8.4 MB

    (void)hipFuncSetAttribute(reinterpret_cast<const void*>(&gemm8_kernel),
                              hipFuncAttributeMaxDynamicSharedMemorySize, 131072);

    cvt_w_kernel<<<4096, 256, 0, stream>>>(W, wb);
    ema_scan_kernel<<<512, 256, 0, stream>>>(x, xml, fp, xmix);
    gemm8_kernel<<<(M_DIM / 256) * (N_DIM / 256), 512, 131072, stream>>>(xmix, wb, out);
}